// Round 1
// baseline (566.934 us; speedup 1.0000x reference)
//
#include <hip/hip_runtime.h>

#define N_    2048
#define H_    128
#define B_    4
#define CIN_  3
#define COUT_ 3

// ---------- helpers ----------
__device__ __forceinline__ float gelu_tanh(float x) {
    // jax.nn.gelu(approximate=True) = x * sigmoid(2*0.7978845608*(x + 0.044715 x^3))
    //  = x / (1 + exp(x * (-1.5957691216 - 0.0713548163 x^2)))
    float x2 = x * x;
    float e = __expf(x * fmaf(-0.07135481627f, x2, -1.59576912161f));
    return x / (1.0f + e);
}

// ---------- K0: small-weight precompute ----------
__global__ void prep_kernel(const float* __restrict__ W2, const float* __restrict__ b2,
                            const float* __restrict__ Wo, const float* __restrict__ bo,
                            const float* __restrict__ Wout, const float* __restrict__ bout,
                            float* __restrict__ w2m, float* __restrict__ b2m,
                            float* __restrict__ wf, float* __restrict__ bf) {
    int gid = blockIdx.x * 256 + threadIdx.x;
    if (gid < 768) {                       // w2m[lvl*256+k] = mean_h W2[lvl,k,h]
        const float* r = W2 + (size_t)gid * 128;
        float s = 0.f;
        for (int h = 0; h < 128; ++h) s += r[h];
        w2m[gid] = s * (1.0f / 128.0f);
    } else if (gid < 771) {                // b2m[lvl] = mean(b2[lvl])
        int lvl = gid - 768;
        const float* r = b2 + lvl * 128;
        float s = 0.f;
        for (int h = 0; h < 128; ++h) s += r[h];
        b2m[lvl] = s * (1.0f / 128.0f);
    } else if (gid >= 1024 && gid < 1408) { // wf[h*3+c] = sum_j Wo[h,j]*Wout[j,c]
        int e = gid - 1024;
        int h = e / 3, c = e - 3 * h;
        float s = 0.f;
        for (int j = 0; j < 128; ++j) s = fmaf(Wo[h * 128 + j], Wout[j * 3 + c], s);
        wf[e] = s;
    } else if (gid >= 1408 && gid < 1411) { // bf[c] = sum_j bo[j]*Wout[j,c] + bout[c]
        int c = gid - 1408;
        float s = bout[c];
        for (int j = 0; j < 128; ++j) s = fmaf(bo[j], Wout[j * 3 + c], s);
        bf[c] = s;
    }
}

// ---------- K1: input projection  xp[(b*H+h), n] ----------
__global__ __launch_bounds__(256) void xproj_kernel(const float* __restrict__ x,
                                                    const float* __restrict__ Win,
                                                    const float* __restrict__ b_in,
                                                    float* __restrict__ xp) {
    int gid = blockIdx.x * 256 + threadIdx.x;    // M_*N_ = 512*2048
    int m = gid >> 11;
    int n = gid & 2047;
    int b = m >> 7;
    int h = m & 127;
    const float* xb = x + (size_t)(b * CIN_) * N_ + n;
    float acc = b_in[h];
#pragma unroll
    for (int c = 0; c < CIN_; ++c) acc = fmaf(xb[(size_t)c * N_], Win[c * H_ + h], acc);
    xp[gid] = acc;
}

// ---------- K2: DWT (stride-2, pad 4/3, reversed taps) + pointwise 2->256->1 MLP ----------
__global__ __launch_bounds__(256) void dwt_mlp_kernel(
        const float* __restrict__ src, int loSh,
        const float* __restrict__ wlow, const float* __restrict__ whigh,
        const float* __restrict__ W1l, const float* __restrict__ b1l,
        const float* __restrict__ w2ml, const float* __restrict__ b2ml,
        float* __restrict__ a_out, float* __restrict__ p_out) {
    __shared__ float4 wp[256];
    __shared__ float wls[8], whs[8];
    int tid = threadIdx.x;
    wp[tid] = make_float4(W1l[tid], W1l[256 + tid], b1l[tid], w2ml[tid]);
    if (tid < 8) { wls[tid] = wlow[tid]; whs[tid] = whigh[tid]; }
    __syncthreads();

    int gid = blockIdx.x * 256 + tid;
    int Lo  = 1 << loSh;
    int m   = gid >> loSh;
    int i   = gid & (Lo - 1);
    int L   = Lo << 1;
    const float* row = src + (size_t)m * L;
    int j0 = 2 * i - 4;
    float xw[8];
#pragma unroll
    for (int t = 0; t < 8; ++t) {
        int j = j0 + t;
        xw[t] = ((unsigned)j < (unsigned)L) ? row[j] : 0.f;
    }
    float a = 0.f, d = 0.f;
#pragma unroll
    for (int t = 0; t < 8; ++t) {
        a = fmaf(xw[t], wls[7 - t], a);
        d = fmaf(xw[t], whs[7 - t], d);
    }
    float acc = 0.f;
#pragma unroll 8
    for (int kk = 0; kk < 256; ++kk) {
        float4 w = wp[kk];
        float t = fmaf(a, w.x, fmaf(d, w.y, w.z));
        acc = fmaf(gelu_tanh(t), w.w, acc);
    }
    a_out[gid] = a;
    p_out[gid] = acc + b2ml[0];
}

// ---------- K3: IDWT (zero-upsample, pad 4/4, forward taps) ----------
__global__ __launch_bounds__(256) void idwt_kernel(
        const float* __restrict__ aSrc, const float* __restrict__ dSrc,
        int loutSh, const float* __restrict__ wlow, const float* __restrict__ whigh,
        float* __restrict__ out) {
    __shared__ float wls[8], whs[8];
    int tid = threadIdx.x;
    if (tid < 8) { wls[tid] = wlow[tid]; whs[tid] = whigh[tid]; }
    __syncthreads();
    int gid  = blockIdx.x * 256 + tid;
    int Lout = 1 << loutSh;
    int L    = Lout >> 1;
    int m    = gid >> loutSh;
    int ii   = gid & (Lout - 1);
    const float* ar = aSrc + (size_t)m * L;
    const float* dr = dSrc + (size_t)m * L;
    int podd = ii & 1;
    int off0 = (ii >> 1) - 2 + podd;
    float r = 0.f;
#pragma unroll
    for (int s = 0; s < 4; ++s) {
        int idx = off0 + s;
        bool ok = (unsigned)idx < (unsigned)L;
        float av = ok ? ar[idx] : 0.f;
        float dv = ok ? dr[idx] : 0.f;
        r = fmaf(av, wls[2 * s + podd], r);
        r = fmaf(dv, whs[2 * s + podd], r);
    }
    out[gid] = r;
}

// ---------- K4: transpose (B,H,N) -> (B,N,H) ----------
__global__ void transpose_kernel(const float* __restrict__ r0, float* __restrict__ seqT) {
    __shared__ float t[32][33];
    int b = blockIdx.z, hT = blockIdx.y, nT = blockIdx.x;
    int tx = threadIdx.x, ty = threadIdx.y;
    int n = nT * 32 + tx;
#pragma unroll
    for (int i = 0; i < 4; ++i) {
        int h = hT * 32 + ty + i * 8;
        t[ty + i * 8][tx] = r0[((size_t)(b * H_ + h)) * N_ + n];
    }
    __syncthreads();
    int h2 = hT * 32 + tx;
#pragma unroll
    for (int i = 0; i < 4; ++i) {
        int n2 = nT * 32 + ty + i * 8;
        seqT[((size_t)(b * N_ + n2)) * H_ + h2] = t[tx][ty + i * 8];
    }
}

// ---------- K5: QKV projection, outputs laid out (b,head,n,dh) ----------
__global__ __launch_bounds__(384) void qkv_kernel(
        const float* __restrict__ seqT,
        const float* __restrict__ Wq, const float* __restrict__ bq,
        const float* __restrict__ Wk, const float* __restrict__ bk,
        const float* __restrict__ Wv, const float* __restrict__ bv,
        float* __restrict__ qB, float* __restrict__ kB, float* __restrict__ vB) {
    __shared__ float As[16 * 128];
    int tid = threadIdx.x;
    int rowbase = blockIdx.x * 16;      // global row in [0, 8192)
    for (int idx = tid; idx < 2048; idx += 384)
        As[idx] = seqT[(size_t)rowbase * 128 + idx];
    __syncthreads();

    const float* W; const float* bias; float* dst; int jj;
    if (tid < 128)      { W = Wq; bias = bq; dst = qB; jj = tid; }
    else if (tid < 256) { W = Wk; bias = bk; dst = kB; jj = tid - 128; }
    else                { W = Wv; bias = bv; dst = vB; jj = tid - 256; }

    float acc[16];
#pragma unroll
    for (int r = 0; r < 16; ++r) acc[r] = 0.f;
    for (int h = 0; h < 128; ++h) {
        float w = W[h * 128 + jj];
#pragma unroll
        for (int r = 0; r < 16; ++r) acc[r] = fmaf(As[r * 128 + h], w, acc[r]);
    }
    float bb = bias[jj];
    int head = jj >> 4, t = jj & 15;
    int b  = rowbase >> 11;
    int n0 = rowbase & 2047;
    size_t obase = ((size_t)(b * 8 + head) * N_) * 16 + t;
#pragma unroll
    for (int r = 0; r < 16; ++r)
        dst[obase + (size_t)(n0 + r) * 16] = acc[r] + bb;
}

// ---------- K6: flash attention, query-per-lane ----------
#define DOT4(acc, qq, aa) do { acc = fmaf(qq.x, aa.x, acc); acc = fmaf(qq.y, aa.y, acc); \
                               acc = fmaf(qq.z, aa.z, acc); acc = fmaf(qq.w, aa.w, acc); } while (0)
#define SCALE4(oo, c)     do { oo.x *= c; oo.y *= c; oo.z *= c; oo.w *= c; } while (0)
#define AXPY4(oo, p, aa)  do { oo.x = fmaf(p, aa.x, oo.x); oo.y = fmaf(p, aa.y, oo.y); \
                               oo.z = fmaf(p, aa.z, oo.z); oo.w = fmaf(p, aa.w, oo.w); } while (0)

__global__ __launch_bounds__(128) void attn_kernel(
        const float* __restrict__ qb, const float* __restrict__ kb,
        const float* __restrict__ vb, float* __restrict__ ot) {
    __shared__ float4 kt4[256];   // 64 keys x 16
    __shared__ float4 vt4[256];
    int tid  = threadIdx.x;
    int qblk = blockIdx.x & 15;
    int bh   = blockIdx.x >> 4;   // 0..31
    int n    = qblk * 128 + tid;

    const float4* ksrc = (const float4*)(kb + (size_t)bh * N_ * 16);
    const float4* vsrc = (const float4*)(vb + (size_t)bh * N_ * 16);
    const float4* qrow = (const float4*)(qb + ((size_t)bh * N_ + n) * 16);
    float4 q0 = qrow[0], q1 = qrow[1], q2 = qrow[2], q3 = qrow[3];
    const float sc = 0.25f;       // dh^-0.5
    SCALE4(q0, sc); SCALE4(q1, sc); SCALE4(q2, sc); SCALE4(q3, sc);

    float mrun = -3.0e38f, lrun = 0.f;
    float4 o0 = {0,0,0,0}, o1 = o0, o2 = o0, o3 = o0;

    for (int kb0 = 0; kb0 < N_; kb0 += 64) {
        __syncthreads();
        int src0 = kb0 * 4;       // float4 index of tile start
        kt4[tid]       = ksrc[src0 + tid];
        kt4[tid + 128] = ksrc[src0 + tid + 128];
        vt4[tid]       = vsrc[src0 + tid];
        vt4[tid + 128] = vsrc[src0 + tid + 128];
        __syncthreads();

        for (int c0 = 0; c0 < 64; c0 += 32) {
            float sv[32];
            float cmax = -3.0e38f;
#pragma unroll
            for (int c = 0; c < 32; ++c) {
                int kr = (c0 + c) * 4;
                float4 a0 = kt4[kr], a1 = kt4[kr+1], a2 = kt4[kr+2], a3 = kt4[kr+3];
                float s = 0.f;
                DOT4(s, q0, a0); DOT4(s, q1, a1); DOT4(s, q2, a2); DOT4(s, q3, a3);
                sv[c] = s;
                cmax = fmaxf(cmax, s);
            }
            float mn   = fmaxf(mrun, cmax);
            float corr = __expf(mrun - mn);
            lrun *= corr;
            SCALE4(o0, corr); SCALE4(o1, corr); SCALE4(o2, corr); SCALE4(o3, corr);
#pragma unroll
            for (int c = 0; c < 32; ++c) {
                float p = __expf(sv[c] - mn);
                lrun += p;
                int vr = (c0 + c) * 4;
                float4 b0 = vt4[vr], b1 = vt4[vr+1], b2 = vt4[vr+2], b3 = vt4[vr+3];
                AXPY4(o0, p, b0); AXPY4(o1, p, b1); AXPY4(o2, p, b2); AXPY4(o3, p, b3);
            }
            mrun = mn;
        }
    }
    float inv = 1.0f / lrun;
    int b = bh >> 3, head = bh & 7;
    float o[16] = {o0.x,o0.y,o0.z,o0.w, o1.x,o1.y,o1.z,o1.w,
                   o2.x,o2.y,o2.z,o2.w, o3.x,o3.y,o3.z,o3.w};
    size_t base = ((size_t)(b * H_ + head * 16)) * N_ + n;   // ot layout (B,H,N)
#pragma unroll
    for (int j = 0; j < 16; ++j) ot[base + (size_t)j * N_] = o[j] * inv;
}

// ---------- K7: fused output projection  out[b,c,n] ----------
__global__ __launch_bounds__(256) void final_kernel(
        const float* __restrict__ ot, const float* __restrict__ wf,
        const float* __restrict__ bf, float* __restrict__ out) {
    __shared__ float wfs[384];
    __shared__ float bfs[3];
    int tid = threadIdx.x;
    for (int i = tid; i < 384; i += 256) wfs[i] = wf[i];
    if (tid < 3) bfs[tid] = bf[tid];
    __syncthreads();
    int b = blockIdx.x >> 3;
    int n = (blockIdx.x & 7) * 256 + tid;
    const float* col = ot + (size_t)b * H_ * N_ + n;
    float a0 = 0.f, a1 = 0.f, a2 = 0.f;
#pragma unroll 4
    for (int h = 0; h < 128; ++h) {
        float v = col[(size_t)h * N_];
        a0 = fmaf(v, wfs[h * 3 + 0], a0);
        a1 = fmaf(v, wfs[h * 3 + 1], a1);
        a2 = fmaf(v, wfs[h * 3 + 2], a2);
    }
    size_t ob = ((size_t)b * 3) * N_ + n;
    out[ob]          = a0 + bfs[0];
    out[ob + N_]     = a1 + bfs[1];
    out[ob + 2 * N_] = a2 + bfs[2];
}

// ---------- launch ----------
extern "C" void kernel_launch(void* const* d_in, const int* in_sizes, int n_in,
                              void* d_out, int out_size, void* d_ws, size_t ws_size,
                              hipStream_t stream) {
    const float* x    = (const float*)d_in[0];
    const float* wlow = (const float*)d_in[1];
    const float* whigh= (const float*)d_in[2];
    const float* Win  = (const float*)d_in[3];
    const float* b_in = (const float*)d_in[4];
    const float* W1   = (const float*)d_in[5];
    const float* b1   = (const float*)d_in[6];
    const float* W2   = (const float*)d_in[7];
    const float* b2   = (const float*)d_in[8];
    const float* Wq   = (const float*)d_in[9];
    const float* bq   = (const float*)d_in[10];
    const float* Wk   = (const float*)d_in[11];
    const float* bk   = (const float*)d_in[12];
    const float* Wv   = (const float*)d_in[13];
    const float* bv   = (const float*)d_in[14];
    const float* Wo   = (const float*)d_in[15];
    const float* bo   = (const float*)d_in[16];
    const float* Wout = (const float*)d_in[17];
    const float* bout = (const float*)d_in[18];
    float* out = (float*)d_out;

    float* ws = (float*)d_ws;
    size_t off = 0;
    auto alloc = [&](size_t nf) { float* p = ws + off; off += nf; return p; };
    float* xp   = alloc(512 * 2048);   // level-0 input  (B*H, N)
    float* a1   = alloc(512 * 1024);
    float* p0   = alloc(512 * 1024);
    float* a2   = alloc(512 * 512);
    float* p1   = alloc(512 * 512);
    float* a3   = alloc(512 * 256);
    float* p2   = alloc(512 * 256);
    float* r2   = alloc(512 * 512);
    float* r1   = alloc(512 * 1024);
    float* r0   = alloc(512 * 2048);
    float* seqT = alloc(4 * 2048 * 128);
    float* qB   = alloc(4 * 8 * 2048 * 16);
    float* kB   = alloc(4 * 8 * 2048 * 16);
    float* vB   = alloc(4 * 8 * 2048 * 16);
    float* otB  = alloc(4 * 128 * 2048);
    float* w2m  = alloc(768);
    float* b2m  = alloc(16);
    float* wf   = alloc(384);
    float* bf   = alloc(16);
    (void)ws_size; (void)in_sizes; (void)n_in; (void)out_size;

    prep_kernel<<<8, 256, 0, stream>>>(W2, b2, Wo, bo, Wout, bout, w2m, b2m, wf, bf);
    xproj_kernel<<<4096, 256, 0, stream>>>(x, Win, b_in, xp);

    dwt_mlp_kernel<<<2048, 256, 0, stream>>>(xp, 10, wlow, whigh,
                                             W1 + 0,    b1 + 0,   w2m + 0,   b2m + 0, a1, p0);
    dwt_mlp_kernel<<<1024, 256, 0, stream>>>(a1, 9,  wlow, whigh,
                                             W1 + 512,  b1 + 256, w2m + 256, b2m + 1, a2, p1);
    dwt_mlp_kernel<<<512, 256, 0, stream>>>(a2, 8,  wlow, whigh,
                                             W1 + 1024, b1 + 512, w2m + 512, b2m + 2, a3, p2);

    idwt_kernel<<<1024, 256, 0, stream>>>(p2, p2, 9,  wlow, whigh, r2);
    idwt_kernel<<<2048, 256, 0, stream>>>(r2, p1, 10, wlow, whigh, r1);
    idwt_kernel<<<4096, 256, 0, stream>>>(r1, p0, 11, wlow, whigh, r0);

    dim3 tg(64, 4, 4), tb(32, 8);
    transpose_kernel<<<tg, tb, 0, stream>>>(r0, seqT);
    qkv_kernel<<<512, 384, 0, stream>>>(seqT, Wq, bq, Wk, bk, Wv, bv, qB, kB, vB);
    attn_kernel<<<512, 128, 0, stream>>>(qB, kB, vB, otB);
    final_kernel<<<32, 256, 0, stream>>>(otB, wf, bf, out);
}

// Round 2
// 391.255 us; speedup vs baseline: 1.4490x; 1.4490x over previous
//
#include <hip/hip_runtime.h>

#define N_    2048
#define H_    128
#define B_    4
#define CIN_  3
#define COUT_ 3
#define KSPLIT 4
#define LOG2E 1.44269504089f

// ---------- helpers ----------
__device__ __forceinline__ float gelu_tanh(float x) {
    // jax.nn.gelu(approximate=True) = x * sigmoid(1.5957691216*(x + 0.044715 x^3))
    // in exp2 domain: x / (1 + 2^(x*(-2.3022089 - 0.10294340 x^2)))
    float x2 = x * x;
    float e = __builtin_amdgcn_exp2f(x * fmaf(-0.10294340397f, x2, -2.30220899f));
    return x * __builtin_amdgcn_rcpf(1.0f + e);
}

// ---------- K0: small-weight precompute ----------
__global__ void prep_kernel(const float* __restrict__ W2, const float* __restrict__ b2,
                            const float* __restrict__ Wo, const float* __restrict__ bo,
                            const float* __restrict__ Wout, const float* __restrict__ bout,
                            float* __restrict__ w2m, float* __restrict__ b2m,
                            float* __restrict__ wf, float* __restrict__ bf) {
    int gid = blockIdx.x * 256 + threadIdx.x;
    if (gid < 768) {
        const float* r = W2 + (size_t)gid * 128;
        float s = 0.f;
        for (int h = 0; h < 128; ++h) s += r[h];
        w2m[gid] = s * (1.0f / 128.0f);
    } else if (gid < 771) {
        int lvl = gid - 768;
        const float* r = b2 + lvl * 128;
        float s = 0.f;
        for (int h = 0; h < 128; ++h) s += r[h];
        b2m[lvl] = s * (1.0f / 128.0f);
    } else if (gid >= 1024 && gid < 1408) {
        int e = gid - 1024;
        int h = e / 3, c = e - 3 * h;
        float s = 0.f;
        for (int j = 0; j < 128; ++j) s = fmaf(Wo[h * 128 + j], Wout[j * 3 + c], s);
        wf[e] = s;
    } else if (gid >= 1408 && gid < 1411) {
        int c = gid - 1408;
        float s = bout[c];
        for (int j = 0; j < 128; ++j) s = fmaf(bo[j], Wout[j * 3 + c], s);
        bf[c] = s;
    }
}

// ---------- K1: input projection ----------
__global__ __launch_bounds__(256) void xproj_kernel(const float* __restrict__ x,
                                                    const float* __restrict__ Win,
                                                    const float* __restrict__ b_in,
                                                    float* __restrict__ xp) {
    int gid = blockIdx.x * 256 + threadIdx.x;
    int m = gid >> 11;
    int n = gid & 2047;
    int b = m >> 7;
    int h = m & 127;
    const float* xb = x + (size_t)(b * CIN_) * N_ + n;
    float acc = b_in[h];
#pragma unroll
    for (int c = 0; c < CIN_; ++c) acc = fmaf(xb[(size_t)c * N_], Win[c * H_ + h], acc);
    xp[gid] = acc;
}

// ---------- K2: DWT + pointwise 2->256->1 MLP ----------
__global__ __launch_bounds__(256) void dwt_mlp_kernel(
        const float* __restrict__ src, int loSh,
        const float* __restrict__ wlow, const float* __restrict__ whigh,
        const float* __restrict__ W1l, const float* __restrict__ b1l,
        const float* __restrict__ w2ml, const float* __restrict__ b2ml,
        float* __restrict__ a_out, float* __restrict__ p_out) {
    __shared__ float4 wp[256];
    __shared__ float wls[8], whs[8];
    int tid = threadIdx.x;
    wp[tid] = make_float4(W1l[tid], W1l[256 + tid], b1l[tid], w2ml[tid]);
    if (tid < 8) { wls[tid] = wlow[tid]; whs[tid] = whigh[tid]; }
    __syncthreads();

    int gid = blockIdx.x * 256 + tid;
    int Lo  = 1 << loSh;
    int m   = gid >> loSh;
    int i   = gid & (Lo - 1);
    int L   = Lo << 1;
    const float* row = src + (size_t)m * L;
    int j0 = 2 * i - 4;
    float xw[8];
#pragma unroll
    for (int t = 0; t < 8; ++t) {
        int j = j0 + t;
        xw[t] = ((unsigned)j < (unsigned)L) ? row[j] : 0.f;
    }
    float a = 0.f, d = 0.f;
#pragma unroll
    for (int t = 0; t < 8; ++t) {
        a = fmaf(xw[t], wls[7 - t], a);
        d = fmaf(xw[t], whs[7 - t], d);
    }
    float acc = 0.f;
#pragma unroll 8
    for (int kk = 0; kk < 256; ++kk) {
        float4 w = wp[kk];
        float t = fmaf(a, w.x, fmaf(d, w.y, w.z));
        acc = fmaf(gelu_tanh(t), w.w, acc);
    }
    a_out[gid] = a;
    p_out[gid] = acc + b2ml[0];
}

// ---------- K3: IDWT ----------
__global__ __launch_bounds__(256) void idwt_kernel(
        const float* __restrict__ aSrc, const float* __restrict__ dSrc,
        int loutSh, const float* __restrict__ wlow, const float* __restrict__ whigh,
        float* __restrict__ out) {
    __shared__ float wls[8], whs[8];
    int tid = threadIdx.x;
    if (tid < 8) { wls[tid] = wlow[tid]; whs[tid] = whigh[tid]; }
    __syncthreads();
    int gid  = blockIdx.x * 256 + tid;
    int Lout = 1 << loutSh;
    int L    = Lout >> 1;
    int m    = gid >> loutSh;
    int ii   = gid & (Lout - 1);
    const float* ar = aSrc + (size_t)m * L;
    const float* dr = dSrc + (size_t)m * L;
    int podd = ii & 1;
    int off0 = (ii >> 1) - 2 + podd;
    float r = 0.f;
#pragma unroll
    for (int s = 0; s < 4; ++s) {
        int idx = off0 + s;
        bool ok = (unsigned)idx < (unsigned)L;
        float av = ok ? ar[idx] : 0.f;
        float dv = ok ? dr[idx] : 0.f;
        r = fmaf(av, wls[2 * s + podd], r);
        r = fmaf(dv, whs[2 * s + podd], r);
    }
    out[gid] = r;
}

// ---------- K4: transpose (B,H,N) -> (B,N,H) ----------
__global__ void transpose_kernel(const float* __restrict__ r0, float* __restrict__ seqT) {
    __shared__ float t[32][33];
    int b = blockIdx.z, hT = blockIdx.y, nT = blockIdx.x;
    int tx = threadIdx.x, ty = threadIdx.y;
    int n = nT * 32 + tx;
#pragma unroll
    for (int i = 0; i < 4; ++i) {
        int h = hT * 32 + ty + i * 8;
        t[ty + i * 8][tx] = r0[((size_t)(b * H_ + h)) * N_ + n];
    }
    __syncthreads();
    int h2 = hT * 32 + tx;
#pragma unroll
    for (int i = 0; i < 4; ++i) {
        int n2 = nT * 32 + ty + i * 8;
        seqT[((size_t)(b * N_ + n2)) * H_ + h2] = t[tx][ty + i * 8];
    }
}

// ---------- K5: QKV projection ----------
__global__ __launch_bounds__(384) void qkv_kernel(
        const float* __restrict__ seqT,
        const float* __restrict__ Wq, const float* __restrict__ bq,
        const float* __restrict__ Wk, const float* __restrict__ bk,
        const float* __restrict__ Wv, const float* __restrict__ bv,
        float* __restrict__ qB, float* __restrict__ kB, float* __restrict__ vB) {
    __shared__ float As[16 * 128];
    int tid = threadIdx.x;
    int rowbase = blockIdx.x * 16;
    for (int idx = tid; idx < 2048; idx += 384)
        As[idx] = seqT[(size_t)rowbase * 128 + idx];
    __syncthreads();

    const float* W; const float* bias; float* dst; int jj;
    if (tid < 128)      { W = Wq; bias = bq; dst = qB; jj = tid; }
    else if (tid < 256) { W = Wk; bias = bk; dst = kB; jj = tid - 128; }
    else                { W = Wv; bias = bv; dst = vB; jj = tid - 256; }

    float acc[16];
#pragma unroll
    for (int r = 0; r < 16; ++r) acc[r] = 0.f;
    for (int h = 0; h < 128; ++h) {
        float w = W[h * 128 + jj];
#pragma unroll
        for (int r = 0; r < 16; ++r) acc[r] = fmaf(As[r * 128 + h], w, acc[r]);
    }
    float bb = bias[jj];
    int head = jj >> 4, t = jj & 15;
    int b  = rowbase >> 11;
    int n0 = rowbase & 2047;
    size_t obase = ((size_t)(b * 8 + head) * N_) * 16 + t;
#pragma unroll
    for (int r = 0; r < 16; ++r)
        dst[obase + (size_t)(n0 + r) * 16] = acc[r] + bb;
}

// ---------- K6: flash attention, split-K, query-per-lane, exp2 domain ----------
#define DOT4(acc, qq, aa) do { acc = fmaf(qq.x, aa.x, acc); acc = fmaf(qq.y, aa.y, acc); \
                               acc = fmaf(qq.z, aa.z, acc); acc = fmaf(qq.w, aa.w, acc); } while (0)
#define SCALE4(oo, c)     do { oo.x *= c; oo.y *= c; oo.z *= c; oo.w *= c; } while (0)
#define AXPY4(oo, p, aa)  do { oo.x = fmaf(p, aa.x, oo.x); oo.y = fmaf(p, aa.y, oo.y); \
                               oo.z = fmaf(p, aa.z, oo.z); oo.w = fmaf(p, aa.w, oo.w); } while (0)

__global__ __launch_bounds__(128) void attn_kernel(
        const float* __restrict__ qb, const float* __restrict__ kb,
        const float* __restrict__ vb,
        float* __restrict__ part_o, float* __restrict__ part_ml) {
    __shared__ float4 kt4[256];   // 64 keys x 16
    __shared__ float4 vt4[256];
    int tid   = threadIdx.x;
    int blk   = blockIdx.x;        // bh*64 + qblk*4 + split
    int split = blk & (KSPLIT - 1);
    int qblk  = (blk >> 2) & 15;
    int bh    = blk >> 6;          // 0..31
    int n     = qblk * 128 + tid;

    const float4* ksrc = (const float4*)(kb + (size_t)bh * N_ * 16);
    const float4* vsrc = (const float4*)(vb + (size_t)bh * N_ * 16);
    const float4* qrow = (const float4*)(qb + ((size_t)bh * N_ + n) * 16);
    float4 q0 = qrow[0], q1 = qrow[1], q2 = qrow[2], q3 = qrow[3];
    const float sc = 0.25f * LOG2E;   // dh^-0.5 * log2(e): exponentials become 2^x
    SCALE4(q0, sc); SCALE4(q1, sc); SCALE4(q2, sc); SCALE4(q3, sc);

    float mrun = -3.0e38f, lrun = 0.f;
    float4 o0 = {0,0,0,0}, o1 = o0, o2 = o0, o3 = o0;

    int k0base = split * (N_ / KSPLIT);
    for (int kb0 = k0base; kb0 < k0base + N_ / KSPLIT; kb0 += 64) {
        __syncthreads();
        int src0 = kb0 * 4;
        kt4[tid]       = ksrc[src0 + tid];
        kt4[tid + 128] = ksrc[src0 + tid + 128];
        vt4[tid]       = vsrc[src0 + tid];
        vt4[tid + 128] = vsrc[src0 + tid + 128];
        __syncthreads();

        for (int c0 = 0; c0 < 64; c0 += 32) {
            float sv[32];
            float cmax = -3.0e38f;
#pragma unroll
            for (int c = 0; c < 32; ++c) {
                int kr = (c0 + c) * 4;
                float4 a0 = kt4[kr], a1 = kt4[kr+1], a2 = kt4[kr+2], a3 = kt4[kr+3];
                float sA = 0.f, sB = 0.f;
                DOT4(sA, q0, a0); DOT4(sB, q1, a1);
                DOT4(sA, q2, a2); DOT4(sB, q3, a3);
                sv[c] = sA + sB;
                cmax = fmaxf(cmax, sv[c]);
            }
            float mn   = fmaxf(mrun, cmax);
            float corr = __builtin_amdgcn_exp2f(mrun - mn);
            lrun *= corr;
            SCALE4(o0, corr); SCALE4(o1, corr); SCALE4(o2, corr); SCALE4(o3, corr);
#pragma unroll
            for (int c = 0; c < 32; ++c) {
                float p = __builtin_amdgcn_exp2f(sv[c] - mn);
                lrun += p;
                int vr = (c0 + c) * 4;
                float4 b0 = vt4[vr], b1 = vt4[vr+1], b2 = vt4[vr+2], b3 = vt4[vr+3];
                AXPY4(o0, p, b0); AXPY4(o1, p, b1); AXPY4(o2, p, b2); AXPY4(o3, p, b3);
            }
            mrun = mn;
        }
    }
    int qg = bh * N_ + n;
    float4* po = (float4*)(part_o + ((size_t)split * (32 * N_) + qg) * 16);
    po[0] = o0; po[1] = o1; po[2] = o2; po[3] = o3;
    float2* pm = (float2*)(part_ml + ((size_t)split * (32 * N_) + qg) * 2);
    pm[0] = make_float2(mrun, lrun);
}

// ---------- K6b: split-K combine -> ot layout (B,H,N) ----------
__global__ __launch_bounds__(256) void attn_combine_kernel(
        const float* __restrict__ part_o, const float* __restrict__ part_ml,
        float* __restrict__ ot) {
    int qg = blockIdx.x * 256 + threadIdx.x;   // 0..65535
    float m[KSPLIT], l[KSPLIT];
    float M = -3.0e38f;
#pragma unroll
    for (int s = 0; s < KSPLIT; ++s) {
        float2 ml = ((const float2*)part_ml)[(size_t)s * (32 * N_) + qg];
        m[s] = ml.x; l[s] = ml.y;
        M = fmaxf(M, m[s]);
    }
    float w[KSPLIT], lt = 0.f;
#pragma unroll
    for (int s = 0; s < KSPLIT; ++s) {
        w[s] = __builtin_amdgcn_exp2f(m[s] - M);
        lt = fmaf(l[s], w[s], lt);
    }
    float inv = __builtin_amdgcn_rcpf(lt);
    float o[16];
#pragma unroll
    for (int j = 0; j < 16; ++j) o[j] = 0.f;
#pragma unroll
    for (int s = 0; s < KSPLIT; ++s) {
        const float4* po = (const float4*)(part_o + ((size_t)s * (32 * N_) + qg) * 16);
#pragma unroll
        for (int r = 0; r < 4; ++r) {
            float4 v = po[r];
            o[4*r+0] = fmaf(v.x, w[s], o[4*r+0]);
            o[4*r+1] = fmaf(v.y, w[s], o[4*r+1]);
            o[4*r+2] = fmaf(v.z, w[s], o[4*r+2]);
            o[4*r+3] = fmaf(v.w, w[s], o[4*r+3]);
        }
    }
    int bh = qg >> 11, n = qg & 2047;
    int b = bh >> 3, head = bh & 7;
    size_t base = ((size_t)(b * H_ + head * 16)) * N_ + n;
#pragma unroll
    for (int j = 0; j < 16; ++j) ot[base + (size_t)j * N_] = o[j] * inv;
}

// ---------- K7: fused output projection ----------
__global__ __launch_bounds__(256) void final_kernel(
        const float* __restrict__ ot, const float* __restrict__ wf,
        const float* __restrict__ bf, float* __restrict__ out) {
    __shared__ float wfs[384];
    __shared__ float bfs[3];
    int tid = threadIdx.x;
    for (int i = tid; i < 384; i += 256) wfs[i] = wf[i];
    if (tid < 3) bfs[tid] = bf[tid];
    __syncthreads();
    int b = blockIdx.x >> 3;
    int n = (blockIdx.x & 7) * 256 + tid;
    const float* col = ot + (size_t)b * H_ * N_ + n;
    float a0 = 0.f, a1 = 0.f, a2 = 0.f;
#pragma unroll 4
    for (int h = 0; h < 128; ++h) {
        float v = col[(size_t)h * N_];
        a0 = fmaf(v, wfs[h * 3 + 0], a0);
        a1 = fmaf(v, wfs[h * 3 + 1], a1);
        a2 = fmaf(v, wfs[h * 3 + 2], a2);
    }
    size_t ob = ((size_t)b * 3) * N_ + n;
    out[ob]          = a0 + bfs[0];
    out[ob + N_]     = a1 + bfs[1];
    out[ob + 2 * N_] = a2 + bfs[2];
}

// ---------- launch ----------
extern "C" void kernel_launch(void* const* d_in, const int* in_sizes, int n_in,
                              void* d_out, int out_size, void* d_ws, size_t ws_size,
                              hipStream_t stream) {
    const float* x    = (const float*)d_in[0];
    const float* wlow = (const float*)d_in[1];
    const float* whigh= (const float*)d_in[2];
    const float* Win  = (const float*)d_in[3];
    const float* b_in = (const float*)d_in[4];
    const float* W1   = (const float*)d_in[5];
    const float* b1   = (const float*)d_in[6];
    const float* W2   = (const float*)d_in[7];
    const float* b2   = (const float*)d_in[8];
    const float* Wq   = (const float*)d_in[9];
    const float* bq   = (const float*)d_in[10];
    const float* Wk   = (const float*)d_in[11];
    const float* bk   = (const float*)d_in[12];
    const float* Wv   = (const float*)d_in[13];
    const float* bv   = (const float*)d_in[14];
    const float* Wo   = (const float*)d_in[15];
    const float* bo   = (const float*)d_in[16];
    const float* Wout = (const float*)d_in[17];
    const float* bout = (const float*)d_in[18];
    float* out = (float*)d_out;

    float* ws = (float*)d_ws;
    size_t off = 0;
    auto alloc = [&](size_t nf) { float* p = ws + off; off += nf; return p; };
    float* xp   = alloc(512 * 2048);
    float* a1   = alloc(512 * 1024);
    float* p0   = alloc(512 * 1024);
    float* a2   = alloc(512 * 512);
    float* p1   = alloc(512 * 512);
    float* a3   = alloc(512 * 256);
    float* p2   = alloc(512 * 256);
    float* r2   = alloc(512 * 512);
    float* r1   = alloc(512 * 1024);
    float* r0   = alloc(512 * 2048);
    float* seqT = alloc(4 * 2048 * 128);
    float* qB   = alloc(4 * 8 * 2048 * 16);
    float* kB   = alloc(4 * 8 * 2048 * 16);
    float* vB   = alloc(4 * 8 * 2048 * 16);
    float* otB  = alloc(4 * 128 * 2048);
    float* w2m  = alloc(768);
    float* b2m  = alloc(16);
    float* wf   = alloc(384);
    float* bf   = alloc(16);
    // split-K partials overlay the dead xp..seqT region (all consumed before attn runs)
    float* part_o  = ws;                                  // KSPLIT*65536*16 floats
    float* part_ml = ws + (size_t)KSPLIT * 65536 * 16;    // KSPLIT*65536*2 floats
    (void)ws_size; (void)in_sizes; (void)n_in; (void)out_size;

    prep_kernel<<<8, 256, 0, stream>>>(W2, b2, Wo, bo, Wout, bout, w2m, b2m, wf, bf);
    xproj_kernel<<<4096, 256, 0, stream>>>(x, Win, b_in, xp);

    dwt_mlp_kernel<<<2048, 256, 0, stream>>>(xp, 10, wlow, whigh,
                                             W1 + 0,    b1 + 0,   w2m + 0,   b2m + 0, a1, p0);
    dwt_mlp_kernel<<<1024, 256, 0, stream>>>(a1, 9,  wlow, whigh,
                                             W1 + 512,  b1 + 256, w2m + 256, b2m + 1, a2, p1);
    dwt_mlp_kernel<<<512, 256, 0, stream>>>(a2, 8,  wlow, whigh,
                                             W1 + 1024, b1 + 512, w2m + 512, b2m + 2, a3, p2);

    idwt_kernel<<<1024, 256, 0, stream>>>(p2, p2, 9,  wlow, whigh, r2);
    idwt_kernel<<<2048, 256, 0, stream>>>(r2, p1, 10, wlow, whigh, r1);
    idwt_kernel<<<4096, 256, 0, stream>>>(r1, p0, 11, wlow, whigh, r0);

    dim3 tg(64, 4, 4), tb(32, 8);
    transpose_kernel<<<tg, tb, 0, stream>>>(r0, seqT);
    qkv_kernel<<<512, 384, 0, stream>>>(seqT, Wq, bq, Wk, bk, Wv, bv, qB, kB, vB);
    attn_kernel<<<2048, 128, 0, stream>>>(qB, kB, vB, part_o, part_ml);
    attn_combine_kernel<<<256, 256, 0, stream>>>(part_o, part_ml, otB);
    final_kernel<<<32, 256, 0, stream>>>(otB, wf, bf, out);
}

// Round 4
// 372.208 us; speedup vs baseline: 1.5232x; 1.0512x over previous
//
#include <hip/hip_runtime.h>

#define N_    2048
#define H_    128
#define B_    4
#define CIN_  3
#define COUT_ 3
#define LOG2E 1.44269504089f

// ---------- helpers ----------
__device__ __forceinline__ float gelu_tanh(float x) {
    // jax.nn.gelu(approximate=True), exp2 domain
    float x2 = x * x;
    float e = __builtin_amdgcn_exp2f(x * fmaf(-0.10294340397f, x2, -2.30220899f));
    return x * __builtin_amdgcn_rcpf(1.0f + e);
}

// ---------- K0: small-weight precompute ----------
__global__ void prep_kernel(const float* __restrict__ W2, const float* __restrict__ b2,
                            const float* __restrict__ Wo, const float* __restrict__ bo,
                            const float* __restrict__ Wout, const float* __restrict__ bout,
                            float* __restrict__ w2m, float* __restrict__ b2m,
                            float* __restrict__ wf, float* __restrict__ bf) {
    int gid = blockIdx.x * 256 + threadIdx.x;
    if (gid < 768) {
        const float* r = W2 + (size_t)gid * 128;
        float s = 0.f;
        for (int h = 0; h < 128; ++h) s += r[h];
        w2m[gid] = s * (1.0f / 128.0f);
    } else if (gid < 771) {
        int lvl = gid - 768;
        const float* r = b2 + lvl * 128;
        float s = 0.f;
        for (int h = 0; h < 128; ++h) s += r[h];
        b2m[lvl] = s * (1.0f / 128.0f);
    } else if (gid >= 1024 && gid < 1408) {
        int e = gid - 1024;
        int h = e / 3, c = e - 3 * h;
        float s = 0.f;
        for (int j = 0; j < 128; ++j) s = fmaf(Wo[h * 128 + j], Wout[j * 3 + c], s);
        wf[e] = s;
    } else if (gid >= 1408 && gid < 1411) {
        int c = gid - 1408;
        float s = bout[c];
        for (int j = 0; j < 128; ++j) s = fmaf(bo[j], Wout[j * 3 + c], s);
        bf[c] = s;
    }
}

// ---------- K2: DWT + pointwise 2->256->1 MLP (level 0 fuses the input projection) ----------
template<bool FUSEX>
__global__ __launch_bounds__(256) void dwt_mlp_kernel(
        const float* __restrict__ src, int loSh,
        const float* __restrict__ x, const float* __restrict__ Win,
        const float* __restrict__ b_in,
        const float* __restrict__ wlow, const float* __restrict__ whigh,
        const float* __restrict__ W1l, const float* __restrict__ b1l,
        const float* __restrict__ w2ml, const float* __restrict__ b2ml,
        float* __restrict__ a_out, float* __restrict__ p_out) {
    __shared__ float4 wp[256];
    __shared__ float wls[8], whs[8];
    int tid = threadIdx.x;
    wp[tid] = make_float4(W1l[tid], W1l[256 + tid], b1l[tid], w2ml[tid]);
    if (tid < 8) { wls[tid] = wlow[tid]; whs[tid] = whigh[tid]; }
    __syncthreads();

    int gid = blockIdx.x * 256 + tid;
    int Lo  = 1 << loSh;
    int m   = gid >> loSh;
    int i   = gid & (Lo - 1);
    int L   = Lo << 1;
    int j0  = 2 * i - 4;
    float xw[8];
    if (FUSEX) {
        int b = m >> 7, h = m & 127;
        float w0 = Win[h], w1 = Win[128 + h], w2 = Win[256 + h];
        float bi = b_in[h];
        const float* xr = x + (size_t)b * (CIN_ * N_);
#pragma unroll
        for (int t = 0; t < 8; ++t) {
            int j = j0 + t;
            bool ok = (unsigned)j < (unsigned)L;
            int jc = ok ? j : 0;
            float v = bi;
            v = fmaf(xr[jc], w0, v);
            v = fmaf(xr[N_ + jc], w1, v);
            v = fmaf(xr[2 * N_ + jc], w2, v);
            xw[t] = ok ? v : 0.f;
        }
    } else {
        const float* row = src + (size_t)m * L;
#pragma unroll
        for (int t = 0; t < 8; ++t) {
            int j = j0 + t;
            xw[t] = ((unsigned)j < (unsigned)L) ? row[j] : 0.f;
        }
    }
    float a = 0.f, d = 0.f;
#pragma unroll
    for (int t = 0; t < 8; ++t) {
        a = fmaf(xw[t], wls[7 - t], a);
        d = fmaf(xw[t], whs[7 - t], d);
    }
    float acc = 0.f;
#pragma unroll 8
    for (int kk = 0; kk < 256; ++kk) {
        float4 w = wp[kk];
        float t = fmaf(a, w.x, fmaf(d, w.y, w.z));
        acc = fmaf(gelu_tanh(t), w.w, acc);
    }
    a_out[gid] = a;
    p_out[gid] = acc + b2ml[0];
}

// ---------- K3: IDWT ----------
__global__ __launch_bounds__(256) void idwt_kernel(
        const float* __restrict__ aSrc, const float* __restrict__ dSrc,
        int loutSh, const float* __restrict__ wlow, const float* __restrict__ whigh,
        float* __restrict__ out) {
    __shared__ float wls[8], whs[8];
    int tid = threadIdx.x;
    if (tid < 8) { wls[tid] = wlow[tid]; whs[tid] = whigh[tid]; }
    __syncthreads();
    int gid  = blockIdx.x * 256 + tid;
    int Lout = 1 << loutSh;
    int L    = Lout >> 1;
    int m    = gid >> loutSh;
    int ii   = gid & (Lout - 1);
    const float* ar = aSrc + (size_t)m * L;
    const float* dr = dSrc + (size_t)m * L;
    int podd = ii & 1;
    int off0 = (ii >> 1) - 2 + podd;
    float r = 0.f;
#pragma unroll
    for (int s = 0; s < 4; ++s) {
        int idx = off0 + s;
        bool ok = (unsigned)idx < (unsigned)L;
        float av = ok ? ar[idx] : 0.f;
        float dv = ok ? dr[idx] : 0.f;
        r = fmaf(av, wls[2 * s + podd], r);
        r = fmaf(dv, whs[2 * s + podd], r);
    }
    out[gid] = r;
}

// ---------- K5: QKV projection, reads r0 (B,H,N) directly ----------
__global__ __launch_bounds__(384) void qkv_kernel(
        const float* __restrict__ r0,
        const float* __restrict__ Wq, const float* __restrict__ bq,
        const float* __restrict__ Wk, const float* __restrict__ bk,
        const float* __restrict__ Wv, const float* __restrict__ bv,
        float* __restrict__ qB, float* __restrict__ kB, float* __restrict__ vB) {
    __shared__ float As[16 * 130];
    int tid = threadIdx.x;
    int rowbase = blockIdx.x * 16;       // row = b*N + n
    int b  = rowbase >> 11;
    int n0 = rowbase & 2047;
    for (int idx = tid; idx < 2048; idx += 384) {
        int h = idx >> 4;
        int r = idx & 15;
        As[r * 130 + h] = r0[((size_t)(b * H_ + h)) * N_ + n0 + r];
    }
    __syncthreads();

    const float* W; const float* bias; float* dst; int jj;
    if (tid < 128)      { W = Wq; bias = bq; dst = qB; jj = tid; }
    else if (tid < 256) { W = Wk; bias = bk; dst = kB; jj = tid - 128; }
    else                { W = Wv; bias = bv; dst = vB; jj = tid - 256; }

    float acc[16];
#pragma unroll
    for (int r = 0; r < 16; ++r) acc[r] = 0.f;
    for (int h = 0; h < 128; ++h) {
        float w = W[h * 128 + jj];
#pragma unroll
        for (int r = 0; r < 16; ++r) acc[r] = fmaf(As[r * 130 + h], w, acc[r]);
    }
    float bb = bias[jj];
    int head = jj >> 4, t = jj & 15;
    size_t obase = ((size_t)(b * 8 + head) * N_) * 16 + t;
#pragma unroll
    for (int r = 0; r < 16; ++r)
        dst[obase + (size_t)(n0 + r) * 16] = acc[r] + bb;
}

// ---------- K6: flash attention, split-K, 2 queries/lane, exp2 domain, defer-max ----------
#define DOT4(acc, qq, aa) do { acc = fmaf(qq.x, aa.x, acc); acc = fmaf(qq.y, aa.y, acc); \
                               acc = fmaf(qq.z, aa.z, acc); acc = fmaf(qq.w, aa.w, acc); } while (0)
#define SCALE4(oo, c)     do { oo.x *= c; oo.y *= c; oo.z *= c; oo.w *= c; } while (0)
#define AXPY4(oo, p, aa)  do { oo.x = fmaf(p, aa.x, oo.x); oo.y = fmaf(p, aa.y, oo.y); \
                               oo.z = fmaf(p, aa.z, oo.z); oo.w = fmaf(p, aa.w, oo.w); } while (0)

template<int KS>
__global__ __launch_bounds__(128, 4) void attn_kernel(
        const float* __restrict__ qb, const float* __restrict__ kb,
        const float* __restrict__ vb,
        float* __restrict__ part_o, float* __restrict__ part_ml) {
    __shared__ float4 kt4[512];   // 128 keys x 16 floats
    __shared__ float4 vt4[512];
    int tid   = threadIdx.x;
    int blk   = blockIdx.x;        // bh*(8*KS) + qblk*KS + split
    int split = blk % KS;
    int qblk  = (blk / KS) & 7;
    int bh    = blk / (8 * KS);
    int nA    = qblk * 256 + tid;
    int nB    = nA + 128;

    const float4* ksrc = (const float4*)(kb + (size_t)bh * (N_ * 16));
    const float4* vsrc = (const float4*)(vb + (size_t)bh * (N_ * 16));
    const float4* qra  = (const float4*)(qb + ((size_t)bh * N_ + nA) * 16);
    const float4* qrb  = (const float4*)(qb + ((size_t)bh * N_ + nB) * 16);
    const float sc = 0.25f * LOG2E;
    float4 qa0 = qra[0], qa1 = qra[1], qa2 = qra[2], qa3 = qra[3];
    float4 qb0 = qrb[0], qb1 = qrb[1], qb2 = qrb[2], qb3 = qrb[3];
    SCALE4(qa0, sc); SCALE4(qa1, sc); SCALE4(qa2, sc); SCALE4(qa3, sc);
    SCALE4(qb0, sc); SCALE4(qb1, sc); SCALE4(qb2, sc); SCALE4(qb3, sc);

    float mA = -3.0e38f, lA = 0.f, mB = -3.0e38f, lB = 0.f;
    float4 oA0 = {0,0,0,0}, oA1 = oA0, oA2 = oA0, oA3 = oA0;
    float4 oB0 = oA0, oB1 = oA0, oB2 = oA0, oB3 = oA0;

    int k0 = split * (N_ / KS);
    for (int t0 = k0; t0 < k0 + N_ / KS; t0 += 128) {
        __syncthreads();
        const float4* ks = ksrc + t0 * 4;
        const float4* vs = vsrc + t0 * 4;
        kt4[tid] = ks[tid]; kt4[tid+128] = ks[tid+128]; kt4[tid+256] = ks[tid+256]; kt4[tid+384] = ks[tid+384];
        vt4[tid] = vs[tid]; vt4[tid+128] = vs[tid+128]; vt4[tid+256] = vs[tid+256]; vt4[tid+384] = vs[tid+384];
        __syncthreads();

        for (int c0 = 0; c0 < 128; c0 += 8) {
            float svA[8], svB[8];
            float cmA = -3.0e38f, cmB = -3.0e38f;
#pragma unroll
            for (int c = 0; c < 8; ++c) {
                int kr = (c0 + c) * 4;
                float4 k0v = kt4[kr], k1v = kt4[kr+1], k2v = kt4[kr+2], k3v = kt4[kr+3];
                float s0 = 0.f, s1 = 0.f, u0 = 0.f, u1 = 0.f;
                DOT4(s0, qa0, k0v); DOT4(s1, qa1, k1v); DOT4(s0, qa2, k2v); DOT4(s1, qa3, k3v);
                DOT4(u0, qb0, k0v); DOT4(u1, qb1, k1v); DOT4(u0, qb2, k2v); DOT4(u1, qb3, k3v);
                svA[c] = s0 + s1; svB[c] = u0 + u1;
                cmA = fmaxf(cmA, svA[c]); cmB = fmaxf(cmB, svB[c]);
            }
            if (__any((cmA > mA + 8.f) || (cmB > mB + 8.f))) {
                float mnA = fmaxf(mA, cmA), mnB = fmaxf(mB, cmB);
                float cA = __builtin_amdgcn_exp2f(mA - mnA);
                float cB = __builtin_amdgcn_exp2f(mB - mnB);
                lA *= cA; lB *= cB;
                SCALE4(oA0, cA); SCALE4(oA1, cA); SCALE4(oA2, cA); SCALE4(oA3, cA);
                SCALE4(oB0, cB); SCALE4(oB1, cB); SCALE4(oB2, cB); SCALE4(oB3, cB);
                mA = mnA; mB = mnB;
            }
#pragma unroll
            for (int c = 0; c < 8; ++c) {
                float pA = __builtin_amdgcn_exp2f(svA[c] - mA);
                float pB = __builtin_amdgcn_exp2f(svB[c] - mB);
                lA += pA; lB += pB;
                int vr = (c0 + c) * 4;
                float4 v0 = vt4[vr], v1 = vt4[vr+1], v2 = vt4[vr+2], v3 = vt4[vr+3];
                AXPY4(oA0, pA, v0); AXPY4(oA1, pA, v1); AXPY4(oA2, pA, v2); AXPY4(oA3, pA, v3);
                AXPY4(oB0, pB, v0); AXPY4(oB1, pB, v1); AXPY4(oB2, pB, v2); AXPY4(oB3, pB, v3);
            }
        }
    }
    int qgA = bh * N_ + nA, qgB = bh * N_ + nB;
    float4* poA = (float4*)part_o + ((size_t)split * 65536 + qgA) * 4;
    poA[0] = oA0; poA[1] = oA1; poA[2] = oA2; poA[3] = oA3;
    float4* poB = (float4*)part_o + ((size_t)split * 65536 + qgB) * 4;
    poB[0] = oB0; poB[1] = oB1; poB[2] = oB2; poB[3] = oB3;
    ((float2*)part_ml)[(size_t)split * 65536 + qgA] = make_float2(mA, lA);
    ((float2*)part_ml)[(size_t)split * 65536 + qgB] = make_float2(mB, lB);
}

// ---------- K6b: split-K combine fused with final projection ----------
template<int KS>
__global__ __launch_bounds__(512) void combine_final_kernel(
        const float* __restrict__ part_o, const float* __restrict__ part_ml,
        const float* __restrict__ wf, const float* __restrict__ bf,
        float* __restrict__ out) {
    __shared__ float ysh[64 * 129];
    __shared__ float wfs[384];
    __shared__ float bfs[3];
    int tid = threadIdx.x;
    if (tid < 384) wfs[tid] = wf[tid];
    if (tid >= 384 && tid < 387) bfs[tid - 384] = bf[tid - 384];
    int b = blockIdx.x >> 5, nb = blockIdx.x & 31;
    int head = tid >> 6, nl = tid & 63;
    int n = nb * 64 + nl;
    int qg = (b * 8 + head) * N_ + n;

    float m[KS], l[KS];
    float M = -3.0e38f;
#pragma unroll
    for (int s = 0; s < KS; ++s) {
        float2 ml = ((const float2*)part_ml)[(size_t)s * 65536 + qg];
        m[s] = ml.x; l[s] = ml.y;
        M = fmaxf(M, m[s]);
    }
    float w[KS], lt = 0.f;
#pragma unroll
    for (int s = 0; s < KS; ++s) {
        w[s] = __builtin_amdgcn_exp2f(m[s] - M);
        lt = fmaf(l[s], w[s], lt);
    }
    float inv = __builtin_amdgcn_rcpf(lt);
    float o[16];
#pragma unroll
    for (int j = 0; j < 16; ++j) o[j] = 0.f;
#pragma unroll
    for (int s = 0; s < KS; ++s) {
        const float4* po = (const float4*)part_o + ((size_t)s * 65536 + qg) * 4;
#pragma unroll
        for (int r = 0; r < 4; ++r) {
            float4 v = po[r];
            o[4*r+0] = fmaf(v.x, w[s], o[4*r+0]);
            o[4*r+1] = fmaf(v.y, w[s], o[4*r+1]);
            o[4*r+2] = fmaf(v.z, w[s], o[4*r+2]);
            o[4*r+3] = fmaf(v.w, w[s], o[4*r+3]);
        }
    }
    int col = head * 16;
#pragma unroll
    for (int j = 0; j < 16; ++j) ysh[nl * 129 + col + j] = o[j] * inv;
    __syncthreads();
    if (tid < 192) {
        int c = tid >> 6, nl2 = tid & 63;
        float acc = bfs[c];
        const float* yr = ysh + nl2 * 129;
#pragma unroll 4
        for (int h = 0; h < 128; ++h) acc = fmaf(yr[h], wfs[h * 3 + c], acc);
        out[((size_t)b * 3 + c) * N_ + nb * 64 + nl2] = acc;
    }
}

// ---------- launch ----------
extern "C" void kernel_launch(void* const* d_in, const int* in_sizes, int n_in,
                              void* d_out, int out_size, void* d_ws, size_t ws_size,
                              hipStream_t stream) {
    const float* x    = (const float*)d_in[0];
    const float* wlow = (const float*)d_in[1];
    const float* whigh= (const float*)d_in[2];
    const float* Win  = (const float*)d_in[3];
    const float* b_in = (const float*)d_in[4];
    const float* W1   = (const float*)d_in[5];
    const float* b1   = (const float*)d_in[6];
    const float* W2   = (const float*)d_in[7];
    const float* b2   = (const float*)d_in[8];
    const float* Wq   = (const float*)d_in[9];
    const float* bq   = (const float*)d_in[10];
    const float* Wk   = (const float*)d_in[11];
    const float* bk   = (const float*)d_in[12];
    const float* Wv   = (const float*)d_in[13];
    const float* bv   = (const float*)d_in[14];
    const float* Wo   = (const float*)d_in[15];
    const float* bo   = (const float*)d_in[16];
    const float* Wout = (const float*)d_in[17];
    const float* bout = (const float*)d_in[18];
    float* out = (float*)d_out;
    (void)in_sizes; (void)n_in; (void)out_size;

    float* ws = (float*)d_ws;
    // persistent region: qB/kB/vB, each B*HEADS*N*dh = 1,048,576 floats (live through attn)
    float* qBuf  = ws;
    float* kBuf  = ws + 1048576;
    float* vBuf  = ws + 2097152;
    float* base2 = ws + 3145728;
    // dwt/idwt chain (all dead before attn) overlays the partials region
    float* a1 = base2;                 // 524288
    float* p0 = base2 + 524288;        // 524288
    float* a2 = base2 + 1048576;       // 262144
    float* p1 = base2 + 1310720;       // 262144
    float* a3 = base2 + 1572864;       // 131072
    float* p2 = base2 + 1703936;       // 131072
    float* r2 = base2 + 1835008;       // 262144
    float* r1 = base2 + 2097152;       // 524288
    float* r0 = base2 + 2621440;       // 1048576, ends at base2 + 3670016

    // choose split-K by available workspace (constant across calls)
    const size_t need8 = (3145728ull + 8ull * 1048576 + 8ull * 131072 + 2048ull) * 4;
    int KS = (ws_size >= need8) ? 8 : 4;

    float* part_o  = base2;                              // KS * 1048576 floats
    float* part_ml = base2 + (size_t)KS * 1048576;       // KS * 131072 floats
    float* smalls  = part_ml + (size_t)KS * 131072;
    float* w2m = smalls;
    float* b2m = smalls + 768;
    float* wf  = smalls + 771;
    float* bf  = smalls + 1155;

    prep_kernel<<<8, 256, 0, stream>>>(W2, b2, Wo, bo, Wout, bout, w2m, b2m, wf, bf);

    dwt_mlp_kernel<true><<<2048, 256, 0, stream>>>(nullptr, 10, x, Win, b_in, wlow, whigh,
                                                   W1 + 0,    b1 + 0,   w2m + 0,   b2m + 0, a1, p0);
    dwt_mlp_kernel<false><<<1024, 256, 0, stream>>>(a1, 9, nullptr, nullptr, nullptr, wlow, whigh,
                                                    W1 + 512,  b1 + 256, w2m + 256, b2m + 1, a2, p1);
    dwt_mlp_kernel<false><<<512, 256, 0, stream>>>(a2, 8, nullptr, nullptr, nullptr, wlow, whigh,
                                                   W1 + 1024, b1 + 512, w2m + 512, b2m + 2, a3, p2);

    idwt_kernel<<<1024, 256, 0, stream>>>(p2, p2, 9,  wlow, whigh, r2);
    idwt_kernel<<<2048, 256, 0, stream>>>(r2, p1, 10, wlow, whigh, r1);
    idwt_kernel<<<4096, 256, 0, stream>>>(r1, p0, 11, wlow, whigh, r0);

    qkv_kernel<<<512, 384, 0, stream>>>(r0, Wq, bq, Wk, bk, Wv, bv, qBuf, kBuf, vBuf);

    if (KS == 8) {
        attn_kernel<8><<<32 * 8 * 8, 128, 0, stream>>>(qBuf, kBuf, vBuf, part_o, part_ml);
        combine_final_kernel<8><<<128, 512, 0, stream>>>(part_o, part_ml, wf, bf, out);
    } else {
        attn_kernel<4><<<32 * 8 * 4, 128, 0, stream>>>(qBuf, kBuf, vBuf, part_o, part_ml);
        combine_final_kernel<4><<<128, 512, 0, stream>>>(part_o, part_ml, wf, bf, out);
    }
}

// Round 5
// 358.367 us; speedup vs baseline: 1.5820x; 1.0386x over previous
//
#include <hip/hip_runtime.h>

#define N_    2048
#define H_    128
#define B_    4
#define CIN_  3
#define COUT_ 3
#define LOG2E 1.44269504089f

// ---------- helpers ----------
__device__ __forceinline__ float gelu_tanh(float x) {
    // jax.nn.gelu(approximate=True), exp2 domain
    float x2 = x * x;
    float e = __builtin_amdgcn_exp2f(x * fmaf(-0.10294340397f, x2, -2.30220899f));
    return x * __builtin_amdgcn_rcpf(1.0f + e);
}

// ---------- K0: small-weight precompute ----------
// wpack[lvl*256+k] = {W1[lvl,0,k], W1[lvl,1,k], b1[lvl,k], mean_h W2[lvl,k,h]}
__global__ void prep_kernel(const float* __restrict__ W1, const float* __restrict__ b1,
                            const float* __restrict__ W2, const float* __restrict__ b2,
                            const float* __restrict__ Wo, const float* __restrict__ bo,
                            const float* __restrict__ Wout, const float* __restrict__ bout,
                            float4* __restrict__ wpack, float* __restrict__ b2m,
                            float* __restrict__ wf, float* __restrict__ bf) {
    int gid = blockIdx.x * 256 + threadIdx.x;
    if (gid < 768) {
        const float* r = W2 + (size_t)gid * 128;
        float s = 0.f;
        for (int h = 0; h < 128; ++h) s += r[h];
        int lvl = gid >> 8, k = gid & 255;
        wpack[gid] = make_float4(W1[lvl * 512 + k], W1[lvl * 512 + 256 + k],
                                 b1[gid], s * (1.0f / 128.0f));
    } else if (gid < 771) {
        int lvl = gid - 768;
        const float* r = b2 + lvl * 128;
        float s = 0.f;
        for (int h = 0; h < 128; ++h) s += r[h];
        b2m[lvl] = s * (1.0f / 128.0f);
    } else if (gid >= 1024 && gid < 1408) {
        int e = gid - 1024;
        int h = e / 3, c = e - 3 * h;
        float s = 0.f;
        for (int j = 0; j < 128; ++j) s = fmaf(Wo[h * 128 + j], Wout[j * 3 + c], s);
        wf[e] = s;
    } else if (gid >= 1408 && gid < 1411) {
        int c = gid - 1408;
        float s = bout[c];
        for (int j = 0; j < 128; ++j) s = fmaf(bo[j], Wout[j * 3 + c], s);
        bf[c] = s;
    }
}

// ---------- K2: DWT + pointwise 2->256->1 MLP (level 0 fuses the input projection) ----------
// No LDS: filter taps + wpack stream are wave-uniform -> scalar loads.
template<bool FUSEX>
__global__ __launch_bounds__(256) void dwt_mlp_kernel(
        const float* __restrict__ src, int loSh,
        const float* __restrict__ x, const float* __restrict__ Win,
        const float* __restrict__ b_in,
        const float* __restrict__ wlow, const float* __restrict__ whigh,
        const float4* __restrict__ wpack, const float* __restrict__ b2ml,
        float* __restrict__ a_out, float* __restrict__ p_out) {
    int tid = threadIdx.x;
    int gid = blockIdx.x * 256 + tid;
    int Lo  = 1 << loSh;
    int m   = gid >> loSh;
    int i   = gid & (Lo - 1);
    int L   = Lo << 1;
    int j0  = 2 * i - 4;
    float xw[8];
    if (FUSEX) {
        int b = m >> 7, h = m & 127;
        float w0 = Win[h], w1 = Win[128 + h], w2 = Win[256 + h];
        float bi = b_in[h];
        const float* xr = x + (size_t)b * (CIN_ * N_);
#pragma unroll
        for (int t = 0; t < 8; ++t) {
            int j = j0 + t;
            bool ok = (unsigned)j < (unsigned)L;
            int jc = ok ? j : 0;
            float v = bi;
            v = fmaf(xr[jc], w0, v);
            v = fmaf(xr[N_ + jc], w1, v);
            v = fmaf(xr[2 * N_ + jc], w2, v);
            xw[t] = ok ? v : 0.f;
        }
    } else {
        const float* row = src + (size_t)m * L;
#pragma unroll
        for (int t = 0; t < 8; ++t) {
            int j = j0 + t;
            xw[t] = ((unsigned)j < (unsigned)L) ? row[j] : 0.f;
        }
    }
    float a = 0.f, d = 0.f;
#pragma unroll
    for (int t = 0; t < 8; ++t) {
        a = fmaf(xw[t], wlow[7 - t], a);      // uniform -> s_load, hoisted
        d = fmaf(xw[t], whigh[7 - t], d);
    }
    float acc = 0.f;
#pragma unroll 8
    for (int kk = 0; kk < 256; ++kk) {
        float4 w = wpack[kk];                 // uniform -> s_load_dwordx4
        float t = fmaf(a, w.x, fmaf(d, w.y, w.z));
        acc = fmaf(gelu_tanh(t), w.w, acc);
    }
    a_out[gid] = a;
    p_out[gid] = acc + b2ml[0];
}

// ---------- K3: IDWT (no LDS; parity-selected taps in regs) ----------
__global__ __launch_bounds__(256) void idwt_kernel(
        const float* __restrict__ aSrc, const float* __restrict__ dSrc,
        int loutSh, const float* __restrict__ wlow, const float* __restrict__ whigh,
        float* __restrict__ out) {
    int tid  = threadIdx.x;
    int gid  = blockIdx.x * 256 + tid;
    int Lout = 1 << loutSh;
    int L    = Lout >> 1;
    int m    = gid >> loutSh;
    int ii   = gid & (Lout - 1);
    const float* ar = aSrc + (size_t)m * L;
    const float* dr = dSrc + (size_t)m * L;
    int podd = ii & 1;
    int off0 = (ii >> 1) - 2 + podd;
    float wlp[4], whp[4];
#pragma unroll
    for (int s = 0; s < 4; ++s) {             // uniform s_loads + cndmask
        wlp[s] = podd ? wlow[2 * s + 1] : wlow[2 * s];
        whp[s] = podd ? whigh[2 * s + 1] : whigh[2 * s];
    }
    float r = 0.f;
#pragma unroll
    for (int s = 0; s < 4; ++s) {
        int idx = off0 + s;
        bool ok = (unsigned)idx < (unsigned)L;
        float av = ok ? ar[idx] : 0.f;
        float dv = ok ? dr[idx] : 0.f;
        r = fmaf(av, wlp[s], r);
        r = fmaf(dv, whp[s], r);
    }
    out[gid] = r;
}

// ---------- K5: QKV projection, reads r0 (B,H,N) directly; A-tile via uniform scalar loads ----------
__global__ __launch_bounds__(384) void qkv_kernel(
        const float* __restrict__ r0,
        const float* __restrict__ Wq, const float* __restrict__ bq,
        const float* __restrict__ Wk, const float* __restrict__ bk,
        const float* __restrict__ Wv, const float* __restrict__ bv,
        float* __restrict__ qB, float* __restrict__ kB, float* __restrict__ vB) {
    int tid = threadIdx.x;
    int rowbase = blockIdx.x * 16;       // row = b*N + n
    int b  = rowbase >> 11;
    int n0 = rowbase & 2047;

    const float* W; const float* bias; float* dst; int jj;
    if (tid < 128)      { W = Wq; bias = bq; dst = qB; jj = tid; }
    else if (tid < 256) { W = Wk; bias = bk; dst = kB; jj = tid - 128; }
    else                { W = Wv; bias = bv; dst = vB; jj = tid - 256; }

    const float* abase = r0 + (size_t)b * (H_ * N_) + n0;
    float acc[16];
#pragma unroll
    for (int r = 0; r < 16; ++r) acc[r] = 0.f;
    for (int h = 0; h < 128; ++h) {
        float w = W[h * 128 + jj];                    // per-lane coalesced, L1/L2-hit
        const float* ar = abase + (size_t)h * N_;     // uniform -> s_load_dwordx
#pragma unroll
        for (int r = 0; r < 16; ++r) acc[r] = fmaf(ar[r], w, acc[r]);
    }
    float bb = bias[jj];
    int head = jj >> 4, t = jj & 15;
    size_t obase = ((size_t)(b * 8 + head) * N_) * 16 + t;
#pragma unroll
    for (int r = 0; r < 16; ++r)
        dst[obase + (size_t)(n0 + r) * 16] = acc[r] + bb;
}

// ---------- K6: flash attention, split-K, 4 queries/lane, exp2 domain, defer-max ----------
#define DOT4(acc, qq, aa) do { acc = fmaf(qq.x, aa.x, acc); acc = fmaf(qq.y, aa.y, acc); \
                               acc = fmaf(qq.z, aa.z, acc); acc = fmaf(qq.w, aa.w, acc); } while (0)
#define SCALE4(oo, c)     do { oo.x *= c; oo.y *= c; oo.z *= c; oo.w *= c; } while (0)
#define AXPY4(oo, p, aa)  do { oo.x = fmaf(p, aa.x, oo.x); oo.y = fmaf(p, aa.y, oo.y); \
                               oo.z = fmaf(p, aa.z, oo.z); oo.w = fmaf(p, aa.w, oo.w); } while (0)

template<int KS>
__global__ __launch_bounds__(128, 2) void attn_kernel(
        const float* __restrict__ qb, const float* __restrict__ kb,
        const float* __restrict__ vb,
        float* __restrict__ part_o, float* __restrict__ part_ml) {
    __shared__ float4 kt4[512];   // 128 keys x 16 floats
    __shared__ float4 vt4[512];
    int tid   = threadIdx.x;
    int blk   = blockIdx.x;        // bh*(4*KS) + qblk*KS + split
    int split = blk % KS;
    int qblk  = (blk / KS) & 3;
    int bh    = blk / (4 * KS);

    const float4* ksrc = (const float4*)(kb + (size_t)bh * (N_ * 16));
    const float4* vsrc = (const float4*)(vb + (size_t)bh * (N_ * 16));
    const float sc = 0.25f * LOG2E;

    float4 q[4][4];
    float  m[4], l[4];
    float4 o[4][4];
#pragma unroll
    for (int qi = 0; qi < 4; ++qi) {
        const float4* qr = (const float4*)(qb + ((size_t)bh * N_ + qblk * 512 + qi * 128 + tid) * 16);
#pragma unroll
        for (int j = 0; j < 4; ++j) { q[qi][j] = qr[j]; SCALE4(q[qi][j], sc); }
        m[qi] = -3.0e38f; l[qi] = 0.f;
#pragma unroll
        for (int j = 0; j < 4; ++j) o[qi][j] = make_float4(0.f, 0.f, 0.f, 0.f);
    }

    int k0 = split * (N_ / KS);
    for (int t0 = k0; t0 < k0 + N_ / KS; t0 += 128) {
        __syncthreads();
        const float4* ks = ksrc + t0 * 4;
        const float4* vs = vsrc + t0 * 4;
#pragma unroll
        for (int u = 0; u < 4; ++u) {
            kt4[tid + u * 128] = ks[tid + u * 128];
            vt4[tid + u * 128] = vs[tid + u * 128];
        }
        __syncthreads();

        for (int c0 = 0; c0 < 128; c0 += 4) {
            float sv[4][4];
            float cm[4] = {-3.0e38f, -3.0e38f, -3.0e38f, -3.0e38f};
#pragma unroll
            for (int c = 0; c < 4; ++c) {
                int kr = (c0 + c) * 4;
                float4 k0v = kt4[kr], k1v = kt4[kr+1], k2v = kt4[kr+2], k3v = kt4[kr+3];
#pragma unroll
                for (int qi = 0; qi < 4; ++qi) {
                    float s0 = 0.f, s1 = 0.f;
                    DOT4(s0, q[qi][0], k0v); DOT4(s1, q[qi][1], k1v);
                    DOT4(s0, q[qi][2], k2v); DOT4(s1, q[qi][3], k3v);
                    sv[qi][c] = s0 + s1;
                    cm[qi] = fmaxf(cm[qi], sv[qi][c]);
                }
            }
            bool need = (cm[0] > m[0] + 8.f) || (cm[1] > m[1] + 8.f) ||
                        (cm[2] > m[2] + 8.f) || (cm[3] > m[3] + 8.f);
            if (__any(need)) {
#pragma unroll
                for (int qi = 0; qi < 4; ++qi) {
                    float mn = fmaxf(m[qi], cm[qi]);
                    float cr = __builtin_amdgcn_exp2f(m[qi] - mn);
                    l[qi] *= cr;
#pragma unroll
                    for (int j = 0; j < 4; ++j) SCALE4(o[qi][j], cr);
                    m[qi] = mn;
                }
            }
#pragma unroll
            for (int c = 0; c < 4; ++c) {
                int vr = (c0 + c) * 4;
                float4 v0 = vt4[vr], v1 = vt4[vr+1], v2 = vt4[vr+2], v3 = vt4[vr+3];
#pragma unroll
                for (int qi = 0; qi < 4; ++qi) {
                    float p = __builtin_amdgcn_exp2f(sv[qi][c] - m[qi]);
                    l[qi] += p;
                    AXPY4(o[qi][0], p, v0); AXPY4(o[qi][1], p, v1);
                    AXPY4(o[qi][2], p, v2); AXPY4(o[qi][3], p, v3);
                }
            }
        }
    }
#pragma unroll
    for (int qi = 0; qi < 4; ++qi) {
        int qg = bh * N_ + qblk * 512 + qi * 128 + tid;
        float4* po = (float4*)part_o + ((size_t)split * 65536 + qg) * 4;
        po[0] = o[qi][0]; po[1] = o[qi][1]; po[2] = o[qi][2]; po[3] = o[qi][3];
        ((float2*)part_ml)[(size_t)split * 65536 + qg] = make_float2(m[qi], l[qi]);
    }
}

// ---------- K6b: split-K combine fused with final projection ----------
template<int KS>
__global__ __launch_bounds__(512) void combine_final_kernel(
        const float* __restrict__ part_o, const float* __restrict__ part_ml,
        const float* __restrict__ wf, const float* __restrict__ bf,
        float* __restrict__ out) {
    __shared__ float ysh[64 * 129];
    int tid = threadIdx.x;
    int b = blockIdx.x >> 5, nb = blockIdx.x & 31;
    int head = tid >> 6, nl = tid & 63;
    int n = nb * 64 + nl;
    int qg = (b * 8 + head) * N_ + n;

    float m[KS], l[KS];
    float M = -3.0e38f;
#pragma unroll
    for (int s = 0; s < KS; ++s) {
        float2 ml = ((const float2*)part_ml)[(size_t)s * 65536 + qg];
        m[s] = ml.x; l[s] = ml.y;
        M = fmaxf(M, m[s]);
    }
    float w[KS], lt = 0.f;
#pragma unroll
    for (int s = 0; s < KS; ++s) {
        w[s] = __builtin_amdgcn_exp2f(m[s] - M);
        lt = fmaf(l[s], w[s], lt);
    }
    float inv = __builtin_amdgcn_rcpf(lt);
    float o[16];
#pragma unroll
    for (int j = 0; j < 16; ++j) o[j] = 0.f;
#pragma unroll
    for (int s = 0; s < KS; ++s) {
        const float4* po = (const float4*)part_o + ((size_t)s * 65536 + qg) * 4;
#pragma unroll
        for (int r = 0; r < 4; ++r) {
            float4 v = po[r];
            o[4*r+0] = fmaf(v.x, w[s], o[4*r+0]);
            o[4*r+1] = fmaf(v.y, w[s], o[4*r+1]);
            o[4*r+2] = fmaf(v.z, w[s], o[4*r+2]);
            o[4*r+3] = fmaf(v.w, w[s], o[4*r+3]);
        }
    }
    int col = head * 16;
#pragma unroll
    for (int j = 0; j < 16; ++j) ysh[nl * 129 + col + j] = o[j] * inv;
    __syncthreads();
    if (tid < 192) {
        int c = tid >> 6, nl2 = tid & 63;
        float acc = bf[c];
        const float* yr = ysh + nl2 * 129;
#pragma unroll 4
        for (int h = 0; h < 128; ++h) acc = fmaf(yr[h], wf[h * 3 + c], acc);  // wf uniform -> s_load
        out[((size_t)b * 3 + c) * N_ + nb * 64 + nl2] = acc;
    }
}

// ---------- launch ----------
extern "C" void kernel_launch(void* const* d_in, const int* in_sizes, int n_in,
                              void* d_out, int out_size, void* d_ws, size_t ws_size,
                              hipStream_t stream) {
    const float* x    = (const float*)d_in[0];
    const float* wlow = (const float*)d_in[1];
    const float* whigh= (const float*)d_in[2];
    const float* Win  = (const float*)d_in[3];
    const float* b_in = (const float*)d_in[4];
    const float* W1   = (const float*)d_in[5];
    const float* b1   = (const float*)d_in[6];
    const float* W2   = (const float*)d_in[7];
    const float* b2   = (const float*)d_in[8];
    const float* Wq   = (const float*)d_in[9];
    const float* bq   = (const float*)d_in[10];
    const float* Wk   = (const float*)d_in[11];
    const float* bk   = (const float*)d_in[12];
    const float* Wv   = (const float*)d_in[13];
    const float* bv   = (const float*)d_in[14];
    const float* Wo   = (const float*)d_in[15];
    const float* bo   = (const float*)d_in[16];
    const float* Wout = (const float*)d_in[17];
    const float* bout = (const float*)d_in[18];
    float* out = (float*)d_out;
    (void)in_sizes; (void)n_in; (void)out_size;

    float* ws = (float*)d_ws;
    // persistent region: qB/kB/vB, each B*HEADS*N*dh = 1,048,576 floats (live through attn)
    float* qBuf  = ws;
    float* kBuf  = ws + 1048576;
    float* vBuf  = ws + 2097152;
    float* base2 = ws + 3145728;
    // dwt/idwt chain (all dead before attn) overlays the partials region
    float* a1 = base2;                 // 524288
    float* p0 = base2 + 524288;        // 524288
    float* a2 = base2 + 1048576;       // 262144
    float* p1 = base2 + 1310720;       // 262144
    float* a3 = base2 + 1572864;       // 131072
    float* p2 = base2 + 1703936;       // 131072
    float* r2 = base2 + 1835008;       // 262144
    float* r1 = base2 + 2097152;       // 524288
    float* r0 = base2 + 2621440;       // 1048576, ends at base2 + 3670016

    // choose split-K by available workspace (constant across calls)
    const size_t need8 = (3145728ull + 8ull * 1048576 + 8ull * 131072 + 8192ull) * 4;
    int KS = (ws_size >= need8) ? 8 : 4;

    float* part_o  = base2;                              // KS * 1048576 floats
    float* part_ml = base2 + (size_t)KS * 1048576;       // KS * 131072 floats
    float* smalls  = part_ml + (size_t)KS * 131072;      // beyond r0's end for both KS
    float4* wpack = (float4*)smalls;                     // 768 float4 = 3072 floats
    float* b2m = smalls + 3072;                          // 16
    float* wf  = smalls + 3088;                          // 384
    float* bf  = smalls + 3472;                          // 16

    prep_kernel<<<8, 256, 0, stream>>>(W1, b1, W2, b2, Wo, bo, Wout, bout, wpack, b2m, wf, bf);

    dwt_mlp_kernel<true><<<2048, 256, 0, stream>>>(nullptr, 10, x, Win, b_in, wlow, whigh,
                                                   wpack + 0,   b2m + 0, a1, p0);
    dwt_mlp_kernel<false><<<1024, 256, 0, stream>>>(a1, 9, nullptr, nullptr, nullptr, wlow, whigh,
                                                    wpack + 256, b2m + 1, a2, p1);
    dwt_mlp_kernel<false><<<512, 256, 0, stream>>>(a2, 8, nullptr, nullptr, nullptr, wlow, whigh,
                                                   wpack + 512, b2m + 2, a3, p2);

    idwt_kernel<<<1024, 256, 0, stream>>>(p2, p2, 9,  wlow, whigh, r2);
    idwt_kernel<<<2048, 256, 0, stream>>>(r2, p1, 10, wlow, whigh, r1);
    idwt_kernel<<<4096, 256, 0, stream>>>(r1, p0, 11, wlow, whigh, r0);

    qkv_kernel<<<512, 384, 0, stream>>>(r0, Wq, bq, Wk, bk, Wv, bv, qBuf, kBuf, vBuf);

    if (KS == 8) {
        attn_kernel<8><<<32 * 4 * 8, 128, 0, stream>>>(qBuf, kBuf, vBuf, part_o, part_ml);
        combine_final_kernel<8><<<128, 512, 0, stream>>>(part_o, part_ml, wf, bf, out);
    } else {
        attn_kernel<4><<<32 * 4 * 4, 128, 0, stream>>>(qBuf, kBuf, vBuf, part_o, part_ml);
        combine_final_kernel<4><<<128, 512, 0, stream>>>(part_o, part_ml, wf, bf, out);
    }
}